// Round 9
// baseline (730.522 us; speedup 1.0000x reference)
//
#include <hip/hip_runtime.h>

// LIF layer: I = spikes @ W^T + b (fp32), then sequential fp32 LIF scan.
//
// NUMERICS CONTRACT (proven in round 2, absmax=0): each output element of the
// GEMM must be a strictly sequential ascending-k fmaf chain from 0.0f over
// k=0..1023, followed by exactly one fp32 bias add. The scan must be the exact
// op sequence t=v/20 (IEEE div); u=I-t; v=v+u; s=(v>1); v=s?0:v.
// Any blocking change must preserve the per-element rounding sequence.
//
// Round 9: R6/R7/R8 all pinned at 58% VALUBusy regardless of barriers/block
// size, with R8 proving conflicts=0. Missing mechanism (per m97 finding):
// hipcc emits `s_waitcnt vmcnt(0) lgkmcnt(0)` BEFORE every s_barrier. R8
// issues the global prefetch immediately before __syncthreads(), so every
// tile exposes the full HBM/L2 latency at the barrier: 8200 FMA cyc /
// (8200 + drain) ~ 58%. Fix: issue the prefetch AFTER the barrier.
//   per tile t: ds_write buf[t&1] (vmcnt already 0 -> barrier drain free)
//               -> __syncthreads() -> issue loads(t+1) -> FMA buf[t&1]
// The loads drain under the FMA phase; next tile's first ds_write carries
// the vmcnt wait (already satisfied). One barrier/tile stays race-free:
// a wave still in FMA(t, buf p) blocks all others at the t+1 barrier,
// which precedes any t+2 write of buf p. All arithmetic identical to R8.

constexpr int kT   = 100;
constexpr int kB   = 256;
constexpr int kIn  = 1024;
constexpr int kOut = 1024;
constexpr int kM   = kT * kB;          // 25600 GEMM rows

constexpr int BM = 128;
constexpr int BN = 128;
constexpr int BK = 16;
constexpr int NT = kIn / BK;           // 64 k-tiles

// ---------------------------------------------------------------------------
// GEMM: I[M,kOut] = A[M,kIn] * W^T[kOut,kIn] + bias   (fp32, sequential-k FMA)
// 128 threads = 8(tr) x 16(tc); micro-tile 16 rows x 8 cols per thread.
// ---------------------------------------------------------------------------
__global__ __launch_bounds__(128, 2)
void gemm_f32(const float* __restrict__ A,
              const float* __restrict__ W,
              const float* __restrict__ bias,
              float* __restrict__ I)
{
    __shared__ float As[2][BK * BM];   // 2 x 8 KB, k-major linear
    __shared__ float Ws[2][BK * BN];   // 2 x 8 KB, 16B chunk c at slot c^(c>>2)

    const int tid = threadIdx.x;
    const int m0  = blockIdx.y * BM;
    const int n0  = blockIdx.x * BN;

    const int tc = tid & 15;       // cols tc*8 .. +7
    const int tr = tid >> 4;       // rows tr*16 .. +15 (tr 0..7)

    // W-fragment read slots (chunk c stored at c^(c>>2))
    const int pw0 = (((2 * tc    ) ^ ((2 * tc    ) >> 2)) & 31) * 4;
    const int pw1 = (((2 * tc + 1) ^ ((2 * tc + 1) >> 2)) & 31) * 4;

    // staging: thread owns A-row (m0+tid) and W-row (n0+tid), k 0..15 each
    const float* Arow = A + (size_t)(m0 + tid) * kIn;
    const float* Wrow = W + (size_t)(n0 + tid) * kIn;
    const int    wc    = tid >> 2;                       // W chunk 0..31
    const int    wslot = (((wc ^ (wc >> 2)) & 31) * 4) + (tid & 3);

    float4 la[4], lw[4];
#pragma unroll
    for (int i = 0; i < 4; ++i) {
        la[i] = *reinterpret_cast<const float4*>(Arow + i * 4);
        lw[i] = *reinterpret_cast<const float4*>(Wrow + i * 4);
    }

    float acc[16][8];
#pragma unroll
    for (int j = 0; j < 16; ++j)
#pragma unroll
        for (int l = 0; l < 8; ++l) acc[j][l] = 0.0f;

    for (int t = 0; t < NT; ++t) {
        float* Ab = As[t & 1];
        float* Wb = Ws[t & 1];

        // stage current regs into this tile's buffer.
        // A writes: fixed k, lanes -> consecutive m: 2-way (free).
        // W writes: permuted slots spread banks: 2-way (free).
        // (first ds_write carries the vmcnt wait for la/lw — satisfied
        //  long ago, since the loads were issued a full FMA phase earlier)
#pragma unroll
        for (int i = 0; i < 4; ++i) {
            const float* pa = reinterpret_cast<const float*>(&la[i]);
            const float* pw = reinterpret_cast<const float*>(&lw[i]);
#pragma unroll
            for (int kk = 0; kk < 4; ++kk) {
                Ab[(i * 4 + kk) * BM + tid]   = pa[kk];
                Wb[(i * 4 + kk) * BN + wslot] = pw[kk];
            }
        }

        __syncthreads();   // vmcnt already 0 here -> pre-barrier drain is free

        // issue next tile's loads AFTER the barrier: they drain under the
        // FMA phase below instead of being force-drained at the barrier.
        if (t + 1 < NT) {
            const int kn = (t + 1) * BK;
#pragma unroll
            for (int i = 0; i < 4; ++i) {
                la[i] = *reinterpret_cast<const float4*>(Arow + kn + i * 4);
                lw[i] = *reinterpret_cast<const float4*>(Wrow + kn + i * 4);
            }
        }

        // FMA phase: per k, 4 broadcast A-reads + 2 swizzled W-reads + 128 fmaf.
        // k strictly ascending => per-element chain order preserved.
#pragma unroll 4
        for (int k = 0; k < BK; ++k) {
            const float4 a0 = *reinterpret_cast<const float4*>(&Ab[k * BM + tr * 16 +  0]);
            const float4 a1 = *reinterpret_cast<const float4*>(&Ab[k * BM + tr * 16 +  4]);
            const float4 a2 = *reinterpret_cast<const float4*>(&Ab[k * BM + tr * 16 +  8]);
            const float4 a3 = *reinterpret_cast<const float4*>(&Ab[k * BM + tr * 16 + 12]);
            const float4 w0 = *reinterpret_cast<const float4*>(&Wb[k * BN + pw0]);
            const float4 w1 = *reinterpret_cast<const float4*>(&Wb[k * BN + pw1]);
            const float a[16] = {a0.x, a0.y, a0.z, a0.w, a1.x, a1.y, a1.z, a1.w,
                                 a2.x, a2.y, a2.z, a2.w, a3.x, a3.y, a3.z, a3.w};
            const float w[8]  = {w0.x, w0.y, w0.z, w0.w, w1.x, w1.y, w1.z, w1.w};
#pragma unroll
            for (int j = 0; j < 16; ++j)
#pragma unroll
                for (int l = 0; l < 8; ++l)
                    acc[j][l] = fmaf(a[j], w[l], acc[j][l]);
        }
        // no trailing barrier: next iter writes the OTHER buffer
    }

    // epilogue: single fp32 bias add per element, float4 stores
    const float4 b0 = *reinterpret_cast<const float4*>(&bias[n0 + tc * 8]);
    const float4 b1 = *reinterpret_cast<const float4*>(&bias[n0 + tc * 8 + 4]);
    const float bb[8] = {b0.x, b0.y, b0.z, b0.w, b1.x, b1.y, b1.z, b1.w};
#pragma unroll
    for (int j = 0; j < 16; ++j) {
        const int m = m0 + tr * 16 + j;
#pragma unroll
        for (int h = 0; h < 2; ++h) {
            float4 o4;
            o4.x = acc[j][h * 4 + 0] + bb[h * 4 + 0];
            o4.y = acc[j][h * 4 + 1] + bb[h * 4 + 1];
            o4.z = acc[j][h * 4 + 2] + bb[h * 4 + 2];
            o4.w = acc[j][h * 4 + 3] + bb[h * 4 + 3];
            *reinterpret_cast<float4*>(&I[(size_t)m * kOut + n0 + tc * 8 + h * 4]) = o4;
        }
    }
}

// ---------------------------------------------------------------------------
// LIF scan (fp32, exact op order), 4 elements per thread (float4 I/O):
//   t1 = v / 20; u = I - t1; v = v + u; s = v > 1; v = s ? 0 : v
// Iin may alias out (per-thread read-before-write on identical addresses).
// ---------------------------------------------------------------------------
__global__ __launch_bounds__(256)
void lif_scan_f32(const float* Iin, float* out)
{
    const int idx4 = (blockIdx.x * blockDim.x + threadIdx.x) * 4;
    if (idx4 >= kB * kOut) return;

    float v0 = 0.0f, v1 = 0.0f, v2 = 0.0f, v3 = 0.0f;
    for (int t = 0; t < kT; ++t) {
        const size_t off = (size_t)t * (kB * kOut) + idx4;
        const float4 Iv = *reinterpret_cast<const float4*>(&Iin[off]);
        float4 s4;

        { const float t1 = v0 / 20.0f; const float u = Iv.x - t1; v0 = v0 + u;
          const bool s = (v0 > 1.0f); s4.x = s ? 1.0f : 0.0f; if (s) v0 = 0.0f; }
        { const float t1 = v1 / 20.0f; const float u = Iv.y - t1; v1 = v1 + u;
          const bool s = (v1 > 1.0f); s4.y = s ? 1.0f : 0.0f; if (s) v1 = 0.0f; }
        { const float t1 = v2 / 20.0f; const float u = Iv.z - t1; v2 = v2 + u;
          const bool s = (v2 > 1.0f); s4.z = s ? 1.0f : 0.0f; if (s) v2 = 0.0f; }
        { const float t1 = v3 / 20.0f; const float u = Iv.w - t1; v3 = v3 + u;
          const bool s = (v3 > 1.0f); s4.w = s ? 1.0f : 0.0f; if (s) v3 = 0.0f; }

        *reinterpret_cast<float4*>(&out[off]) = s4;
    }
}

extern "C" void kernel_launch(void* const* d_in, const int* in_sizes, int n_in,
                              void* d_out, int out_size, void* d_ws, size_t ws_size,
                              hipStream_t stream) {
    const float* spikes = (const float*)d_in[0];   // [T, B, IN] fp32
    const float* W      = (const float*)d_in[1];   // [OUT, IN] fp32
    const float* bias   = (const float*)d_in[2];   // [OUT] fp32
    float* out = (float*)d_out;                    // [T, B, OUT] fp32 spikes

    const size_t iBytes = (size_t)kM * kOut * sizeof(float);   // 104.9 MB
    dim3 grid(kOut / BN, kM / BM);                 // 8 x 200 = 1600 blocks

    float* Ibuf = (ws_size >= iBytes && d_ws != nullptr) ? (float*)d_ws : out;
    gemm_f32<<<grid, 128, 0, stream>>>(spikes, W, bias, Ibuf);
    lif_scan_f32<<<(kB * kOut) / (256 * 4), 256, 0, stream>>>(Ibuf, out);
}

// Round 10
// 672.224 us; speedup vs baseline: 1.0867x; 1.0867x over previous
//
#include <hip/hip_runtime.h>

// LIF layer: I = spikes @ W^T + b (fp32), then sequential fp32 LIF scan.
//
// NUMERICS CONTRACT (proven in round 2, absmax=0): each output element of the
// GEMM must be a strictly sequential ascending-k fmaf chain from 0.0f over
// k=0..1023, followed by exactly one fp32 bias add. The scan must be the exact
// op sequence t=v/20 (IEEE div); u=I-t; v=v+u; s=(v>1); v=s?0:v.
// Any blocking change must preserve the per-element rounding sequence.
//
// Round 10: all 16x8 variants (R6-R9) pinned at 58% VALUBusy / 16% occ:
// acc[16][8] costs ~250 unified regs -> ~1.3-2 waves/SIMD -> no cross-wave
// overlap of LDS issue and FMA issue. LDS BW itself is 256 B/clk/CU
// (rocminfo), so the pipe is NOT the limit; per-wave issue duty is
// (128 FMA cyc)/(128+~48 ds_read issue) ~ 73% for 8x8 -- the 69% plateau.
// The untried lever: 8x8 tile (acc 64, ~106 live regs) + BK=16 +
// __launch_bounds__(256,4) to force <=128 regs -> 4 waves/SIMD (50% occ),
// so different waves co-issue VALU and LDS. Double-buffered one-barrier
// loop, post-barrier prefetch (R7/R9 structure). W chunk-XOR swizzle kept.
// All arithmetic identical to R3/R5 => bit-identical output.

constexpr int kT   = 100;
constexpr int kB   = 256;
constexpr int kIn  = 1024;
constexpr int kOut = 1024;
constexpr int kM   = kT * kB;          // 25600 GEMM rows

constexpr int BM = 128;
constexpr int BN = 128;
constexpr int BK = 16;
constexpr int NT = kIn / BK;           // 64 k-tiles

// ---------------------------------------------------------------------------
// GEMM: I[M,kOut] = A[M,kIn] * W^T[kOut,kIn] + bias   (fp32, sequential-k FMA)
// 256 threads = 16(tr) x 16(tc); micro-tile 8 rows x 8 cols per thread.
// ---------------------------------------------------------------------------
__global__ __launch_bounds__(256, 4)
void gemm_f32(const float* __restrict__ A,
              const float* __restrict__ W,
              const float* __restrict__ bias,
              float* __restrict__ I)
{
    __shared__ float As[2][BK * BM];   // 2 x 8 KB, k-major linear
    __shared__ float Ws[2][BK * BN];   // 2 x 8 KB, 16B chunk c at slot c^(c>>2)

    const int tid = threadIdx.x;
    const int m0  = blockIdx.y * BM;
    const int n0  = blockIdx.x * BN;

    const int tc = tid & 15;       // cols tc*8 .. +7
    const int tr = tid >> 4;       // rows tr*8 .. +7

    // W-fragment read slots (chunk c stored at c^(c>>2))
    const int pw0 = (((2 * tc    ) ^ ((2 * tc    ) >> 2)) & 31) * 4;
    const int pw1 = (((2 * tc + 1) ^ ((2 * tc + 1) >> 2)) & 31) * 4;

    // staging: thread owns row sr = tid>>1 (0..127), k-half sc0 = (tid&1)*8
    const int sr  = tid >> 1;
    const int sc0 = (tid & 1) * 8;
    const float* Arow = A + (size_t)(m0 + sr) * kIn + sc0;
    const float* Wrow = W + (size_t)(n0 + sr) * kIn + sc0;
    // W staging slot for row sr: chunk c = sr>>2 -> slot (c^(c>>2))*4 + (sr&3)
    const int wslot = ((((sr >> 2) ^ (sr >> 4)) & 31) * 4) + (sr & 3);

    float4 la[2], lw[2];
#pragma unroll
    for (int i = 0; i < 2; ++i) {
        la[i] = *reinterpret_cast<const float4*>(Arow + i * 4);
        lw[i] = *reinterpret_cast<const float4*>(Wrow + i * 4);
    }

    float acc[8][8];
#pragma unroll
    for (int j = 0; j < 8; ++j)
#pragma unroll
        for (int l = 0; l < 8; ++l) acc[j][l] = 0.0f;

    for (int t = 0; t < NT; ++t) {
        float* Ab = As[t & 1];
        float* Wb = Ws[t & 1];

        // stage current regs into this tile's buffer.
        // A writes: fixed k, lanes -> consecutive m: 2-way (free).
        // W writes: permuted slots spread banks: 2-way (free).
#pragma unroll
        for (int i = 0; i < 2; ++i) {
            const float* pa = reinterpret_cast<const float*>(&la[i]);
            const float* pw = reinterpret_cast<const float*>(&lw[i]);
#pragma unroll
            for (int kk = 0; kk < 4; ++kk) {
                const int k = sc0 + i * 4 + kk;
                Ab[k * BM + sr]    = pa[kk];
                Wb[k * BN + wslot] = pw[kk];
            }
        }

        __syncthreads();   // single barrier per tile (race-free: R7 argument)

        // issue next tile's loads AFTER the barrier; drain under FMA phase
        if (t + 1 < NT) {
            const int kn = (t + 1) * BK;
#pragma unroll
            for (int i = 0; i < 2; ++i) {
                la[i] = *reinterpret_cast<const float4*>(Arow + kn + i * 4);
                lw[i] = *reinterpret_cast<const float4*>(Wrow + kn + i * 4);
            }
        }

        // FMA phase: per k, 2 broadcast A-reads + 2 swizzled W-reads + 64 fmaf.
        // k strictly ascending => per-element chain order preserved.
#pragma unroll 4
        for (int k = 0; k < BK; ++k) {
            const float4 a0 = *reinterpret_cast<const float4*>(&Ab[k * BM + tr * 8]);
            const float4 a1 = *reinterpret_cast<const float4*>(&Ab[k * BM + tr * 8 + 4]);
            const float4 w0 = *reinterpret_cast<const float4*>(&Wb[k * BN + pw0]);
            const float4 w1 = *reinterpret_cast<const float4*>(&Wb[k * BN + pw1]);
            const float a[8] = {a0.x, a0.y, a0.z, a0.w, a1.x, a1.y, a1.z, a1.w};
            const float w[8] = {w0.x, w0.y, w0.z, w0.w, w1.x, w1.y, w1.z, w1.w};
#pragma unroll
            for (int j = 0; j < 8; ++j)
#pragma unroll
                for (int l = 0; l < 8; ++l)
                    acc[j][l] = fmaf(a[j], w[l], acc[j][l]);
        }
        // no trailing barrier: next iter writes the OTHER buffer
    }

    // epilogue: single fp32 bias add per element, float4 stores
#pragma unroll
    for (int j = 0; j < 8; ++j) {
        const int m = m0 + tr * 8 + j;
#pragma unroll
        for (int h = 0; h < 2; ++h) {
            const int n = n0 + tc * 8 + h * 4;
            float4 o4;
            o4.x = acc[j][h * 4 + 0] + bias[n + 0];
            o4.y = acc[j][h * 4 + 1] + bias[n + 1];
            o4.z = acc[j][h * 4 + 2] + bias[n + 2];
            o4.w = acc[j][h * 4 + 3] + bias[n + 3];
            *reinterpret_cast<float4*>(&I[(size_t)m * kOut + n]) = o4;
        }
    }
}

// ---------------------------------------------------------------------------
// LIF scan (fp32, exact op order), 4 elements per thread (float4 I/O):
//   t1 = v / 20; u = I - t1; v = v + u; s = v > 1; v = s ? 0 : v
// Iin may alias out (per-thread read-before-write on identical addresses).
// ---------------------------------------------------------------------------
__global__ __launch_bounds__(256)
void lif_scan_f32(const float* Iin, float* out)
{
    const int idx4 = (blockIdx.x * blockDim.x + threadIdx.x) * 4;
    if (idx4 >= kB * kOut) return;

    float v0 = 0.0f, v1 = 0.0f, v2 = 0.0f, v3 = 0.0f;
    for (int t = 0; t < kT; ++t) {
        const size_t off = (size_t)t * (kB * kOut) + idx4;
        const float4 Iv = *reinterpret_cast<const float4*>(&Iin[off]);
        float4 s4;

        { const float t1 = v0 / 20.0f; const float u = Iv.x - t1; v0 = v0 + u;
          const bool s = (v0 > 1.0f); s4.x = s ? 1.0f : 0.0f; if (s) v0 = 0.0f; }
        { const float t1 = v1 / 20.0f; const float u = Iv.y - t1; v1 = v1 + u;
          const bool s = (v1 > 1.0f); s4.y = s ? 1.0f : 0.0f; if (s) v1 = 0.0f; }
        { const float t1 = v2 / 20.0f; const float u = Iv.z - t1; v2 = v2 + u;
          const bool s = (v2 > 1.0f); s4.z = s ? 1.0f : 0.0f; if (s) v2 = 0.0f; }
        { const float t1 = v3 / 20.0f; const float u = Iv.w - t1; v3 = v3 + u;
          const bool s = (v3 > 1.0f); s4.w = s ? 1.0f : 0.0f; if (s) v3 = 0.0f; }

        *reinterpret_cast<float4*>(&out[off]) = s4;
    }
}

extern "C" void kernel_launch(void* const* d_in, const int* in_sizes, int n_in,
                              void* d_out, int out_size, void* d_ws, size_t ws_size,
                              hipStream_t stream) {
    const float* spikes = (const float*)d_in[0];   // [T, B, IN] fp32
    const float* W      = (const float*)d_in[1];   // [OUT, IN] fp32
    const float* bias   = (const float*)d_in[2];   // [OUT] fp32
    float* out = (float*)d_out;                    // [T, B, OUT] fp32 spikes

    const size_t iBytes = (size_t)kM * kOut * sizeof(float);   // 104.9 MB
    dim3 grid(kOut / BN, kM / BM);                 // 8 x 200 = 1600 blocks

    float* Ibuf = (ws_size >= iBytes && d_ws != nullptr) ? (float*)d_ws : out;
    gemm_f32<<<grid, 256, 0, stream>>>(spikes, W, bias, Ibuf);
    lif_scan_f32<<<(kB * kOut) / (256 * 4), 256, 0, stream>>>(Ibuf, out);
}